// Round 4
// baseline (3769.707 us; speedup 1.0000x reference)
//
#include <hip/hip_runtime.h>
#include <hip/hip_bf16.h>

#define SEQ   320
#define HDIM  400
#define GATES 1600
#define NCOL  3200
#define GDW   8     // workgroups per direction in the recurrent kernel
#define RPW   50    // h-rows owned per workgroup (400/8)

// ---------------------------------------------------------------- embeddings
__global__ __launch_bounds__(256) void embed_kernel(
    const int* __restrict__ words, const int* __restrict__ tags,
    const float* __restrict__ wemb, const float* __restrict__ temb,
    float* __restrict__ x)
{
    int i = blockIdx.x * 256 + threadIdx.x;
    if (i >= SEQ * 400) return;
    int t = i / 400, c = i % 400;
    x[i] = (c < 300) ? wemb[(size_t)words[t] * 300 + c]
                     : temb[(size_t)tags[t] * 100 + (c - 300)];
}

// ---------------------------------------------------------------- bias prep
__global__ __launch_bounds__(256) void bias_kernel(
    const float* __restrict__ bihl0,  const float* __restrict__ bhhl0,
    const float* __restrict__ bihl0r, const float* __restrict__ bhhl0r,
    const float* __restrict__ bihl1,  const float* __restrict__ bhhl1,
    const float* __restrict__ bihl1r, const float* __restrict__ bhhl1r,
    const float* __restrict__ mlpb1,
    float* __restrict__ bL0, float* __restrict__ bL1, float* __restrict__ bAB)
{
    int g = blockIdx.x * 256 + threadIdx.x;
    if (g >= NCOL) return;
    if (g < GATES) {
        bL0[g] = bihl0[g] + bhhl0[g];
        bL1[g] = bihl1[g] + bhhl1[g];
        bAB[g] = mlpb1[g];
    } else {
        int q = g - GATES;
        bL0[g] = bihl0r[q] + bhhl0r[q];
        bL1[g] = bihl1r[q] + bhhl1r[q];
        bAB[g] = 0.f;
    }
}

// ---------------------------------------------------------------- tiled SGEMM
__global__ __launch_bounds__(256) void gemm_bias(
    const float* __restrict__ A, int lda, int K,
    const float* __restrict__ B0, const float* __restrict__ B1, int ldb,
    const float* __restrict__ bias, float* __restrict__ C)
{
    __shared__ float As[16][68];   // +4 pad: k-major, conflict-free
    __shared__ float Bs[16][68];
    const int m0 = blockIdx.y * 64, n0 = blockIdx.x * 64;
    const int tid = threadIdx.x, tx = tid & 15, ty = tid >> 4;
    float acc[4][4] = {};
    for (int k0 = 0; k0 < K; k0 += 16) {
        for (int i = tid; i < 1024; i += 256) {
            int r = i >> 4, c = i & 15;
            As[c][r] = A[(size_t)(m0 + r) * lda + k0 + c];
            int n = n0 + r;
            const float* brow = (n < GATES) ? (B0 + (size_t)n * ldb)
                                            : (B1 + (size_t)(n - GATES) * ldb);
            Bs[c][r] = brow[k0 + c];
        }
        __syncthreads();
#pragma unroll
        for (int kk = 0; kk < 16; ++kk) {
            float4 a4 = *(const float4*)&As[kk][ty * 4];
            float4 b4 = *(const float4*)&Bs[kk][tx * 4];
            float av[4] = {a4.x, a4.y, a4.z, a4.w};
            float bv[4] = {b4.x, b4.y, b4.z, b4.w};
#pragma unroll
            for (int i2 = 0; i2 < 4; ++i2)
#pragma unroll
                for (int j2 = 0; j2 < 4; ++j2)
                    acc[i2][j2] += av[i2] * bv[j2];
        }
        __syncthreads();
    }
#pragma unroll
    for (int i2 = 0; i2 < 4; ++i2) {
        int m = m0 + ty * 4 + i2;
#pragma unroll
        for (int j2 = 0; j2 < 4; ++j2) {
            int n = n0 + tx * 4 + j2;
            C[(size_t)m * NCOL + n] = acc[i2][j2] + bias[n];
        }
    }
}

// ---------------------------------------------------------------- recurrence
// R4: same 8-WG/direction sync domain, but weights ACTUALLY in registers:
// 1024 threads = 16 waves = (gate x k-quarter); 100 fp32 weights/thread
// (~115 live VGPRs < 128 budget at __launch_bounds__(1024,4) -> no spill).
// h_prev broadcast-read from LDS; 16 partials reduced via padded LDS array.
// h history in `out` pre-filled with 0xFFFFFFFF sentinel (data = ready flag).
__global__ __launch_bounds__(1024, 4) void lstm_layer(
    const float* __restrict__ gates,   // SEQ x 3200 (x@W_ih^T + biases)
    const float* __restrict__ whh_f, const float* __restrict__ whh_b,
    const float* __restrict__ h0f, const float* __restrict__ h0b,
    const float* __restrict__ c0f, const float* __restrict__ c0b,
    float* out)
{
    __shared__ float h_lds[400];
    __shared__ float part[16][52];     // stride 52: conflict-free row access
    const int tid = threadIdx.x;
    const int dir = blockIdx.x >> 3;
    const int wg  = blockIdx.x & 7;
    const int j0  = wg * RPW;
    const float* whh = dir ? whh_b : whh_f;
    const float* h0d = dir ? h0b : h0f;
    const float* c0d = dir ? c0b : c0f;

    const int w    = tid >> 6;         // wave 0..15
    const int lane = tid & 63;
    const int g    = w & 3;            // gate
    const int kq   = w >> 2;           // k-quarter (100 elements)
    const int jrow = j0 + (lane < RPW ? lane : RPW - 1);

    // ---- one-time: 100 W_hh weights per thread into registers (25 float4)
    float wr[100];
    {
        const float4* wp =
            (const float4*)(whh + (size_t)(g * 400 + jrow) * 400 + kq * 100);
#pragma unroll
        for (int k = 0; k < 25; ++k) {
            float4 t = wp[k];
            wr[4 * k + 0] = t.x; wr[4 * k + 1] = t.y;
            wr[4 * k + 2] = t.z; wr[4 * k + 3] = t.w;
        }
    }

    const int pc = tid % 100;          // poll chunk (16B)
    const int pr = tid / 100;          // poll replica; replicas 0..3 active
    float c_prev = (tid < RPW) ? c0d[j0 + tid] : 0.f;

    for (int s = 0; s < 320; ++s) {
        const int row = dir ? (319 - s) : s;

        // gate prefetch for activation threads (independent of h_prev)
        float gv0 = 0.f, gv1 = 0.f, gv2 = 0.f, gv3 = 0.f;
        if (tid < RPW) {
            const float* gx = gates + (size_t)row * NCOL + dir * GATES + j0 + tid;
            gv0 = gx[0]; gv1 = gx[400]; gv2 = gx[800]; gv3 = gx[1200];
        }

        if (s == 0) {
            if (tid < 100) ((float4*)h_lds)[tid] = ((const float4*)h0d)[tid];
        } else if (pr < 4) {
            const int rp = dir ? (row + 1) : (row - 1);
            const unsigned long long* src =
                (const unsigned long long*)(out + (size_t)rp * 800 + dir * 400) + pc * 2;
            unsigned long long a, b;
            for (;;) {
                a = __hip_atomic_load(src,     __ATOMIC_RELAXED, __HIP_MEMORY_SCOPE_AGENT);
                b = __hip_atomic_load(src + 1, __ATOMIC_RELAXED, __HIP_MEMORY_SCOPE_AGENT);
                if ((unsigned)a != 0xFFFFFFFFu && (unsigned)(a >> 32) != 0xFFFFFFFFu &&
                    (unsigned)b != 0xFFFFFFFFu && (unsigned)(b >> 32) != 0xFFFFFFFFu)
                    break;
            }
            float* dst = &h_lds[pc * 4];
            dst[0] = __uint_as_float((unsigned)a);
            dst[1] = __uint_as_float((unsigned)(a >> 32));
            dst[2] = __uint_as_float((unsigned)b);
            dst[3] = __uint_as_float((unsigned)(b >> 32));
        }
        __syncthreads();

        // partial dot over this wave's k-quarter; h broadcast from LDS
        {
            const float4* h4 = (const float4*)&h_lds[kq * 100];
            float a0 = 0.f, a1 = 0.f, a2 = 0.f, a3 = 0.f;
#pragma unroll
            for (int k = 0; k < 25; ++k) {
                float4 hv = h4[k];
                a0 += wr[4 * k + 0] * hv.x;
                a1 += wr[4 * k + 1] * hv.y;
                a2 += wr[4 * k + 2] * hv.z;
                a3 += wr[4 * k + 3] * hv.w;
            }
            if (lane < RPW) part[w][lane] = (a0 + a1) + (a2 + a3);
        }
        __syncthreads();

        if (tid < RPW) {
            float gi = gv0 + ((part[0][tid] + part[4][tid]) + (part[8][tid]  + part[12][tid]));
            float gf = gv1 + ((part[1][tid] + part[5][tid]) + (part[9][tid]  + part[13][tid]));
            float gg = gv2 + ((part[2][tid] + part[6][tid]) + (part[10][tid] + part[14][tid]));
            float go = gv3 + ((part[3][tid] + part[7][tid]) + (part[11][tid] + part[15][tid]));
            float iv = 1.f / (1.f + __expf(-gi));
            float fv = 1.f / (1.f + __expf(-gf));
            float ov = 1.f / (1.f + __expf(-go));
            float tg = 1.f - 2.f / (1.f + __expf(2.f * gg));
            c_prev = fv * c_prev + iv * tg;
            float tc = 1.f - 2.f / (1.f + __expf(2.f * c_prev));
            float hv = ov * tc;
            __hip_atomic_store((unsigned*)(out + (size_t)row * 800 + dir * 400 + j0 + tid),
                               __float_as_uint(hv), __ATOMIC_RELAXED,
                               __HIP_MEMORY_SCOPE_AGENT);
        }
        // hazards: h_lds rewritten only after barrier-2 (all dot reads done);
        // part[] rewritten only after barrier-1 of next step, reached by act
        // threads only after they consumed part[]. safe with 2 barriers/step.
    }
}

// ---------------------------------------------------------------- fused scorer
__global__ __launch_bounds__(256) void scores_kernel(
    const float* __restrict__ ab, const float* __restrict__ w2,
    const float* __restrict__ b2, float* __restrict__ out)
{
    __shared__ float a_s[16 * 132];
    __shared__ float b_s[16 * 132];
    __shared__ float w_s[128];
    const int tx = threadIdx.x, ty = threadIdx.y;
    const int tid = ty * 16 + tx;
    const int n0 = blockIdx.y * 16, d0 = blockIdx.x * 16;
    float acc = 0.f;
    for (int kc = 0; kc < 1600; kc += 128) {
        for (int i = tid; i < 16 * 128; i += 256) {
            int r = i >> 7, c = i & 127;
            a_s[r * 132 + c] = ab[(size_t)(n0 + r) * NCOL + kc + c];
            b_s[r * 132 + c] = ab[(size_t)(d0 + r) * NCOL + 1600 + kc + c];
        }
        if (tid < 128) w_s[tid] = w2[kc + tid];
        __syncthreads();
#pragma unroll
        for (int k = 0; k < 128; k += 4) {
            float4 av = *(const float4*)&a_s[ty * 132 + k];
            float4 bv = *(const float4*)&b_s[tx * 132 + k];
            float4 wv = *(const float4*)&w_s[k];
            acc += fmaxf(av.x + bv.x, 0.f) * wv.x;
            acc += fmaxf(av.y + bv.y, 0.f) * wv.y;
            acc += fmaxf(av.z + bv.z, 0.f) * wv.z;
            acc += fmaxf(av.w + bv.w, 0.f) * wv.w;
        }
        __syncthreads();
    }
    int n = n0 + ty, d = d0 + tx;
    out[(size_t)(n + 1) * 321 + (d + 1)] = (n == d) ? 0.f : (acc + b2[0]);
}

__global__ void border_kernel(float* out) {
    int i = blockIdx.x * 256 + threadIdx.x;
    if (i < 321) {
        out[i]               = (i == 0) ? 1.f : 0.f;  // row 0
        out[(size_t)i * 321] = (i == 0) ? 1.f : 0.f;  // col 0
    }
}

// ---------------------------------------------------------------- launcher
extern "C" void kernel_launch(void* const* d_in, const int* in_sizes, int n_in,
                              void* d_out, int out_size, void* d_ws, size_t ws_size,
                              hipStream_t stream)
{
    const int*   words    = (const int*)d_in[0];
    const int*   tags     = (const int*)d_in[1];
    const float* wemb     = (const float*)d_in[3];
    const float* temb     = (const float*)d_in[4];
    const float* h0       = (const float*)d_in[5];
    const float* c0       = (const float*)d_in[6];
    const float* w_ih_l0  = (const float*)d_in[7];
    const float* w_hh_l0  = (const float*)d_in[8];
    const float* b_ih_l0  = (const float*)d_in[9];
    const float* b_hh_l0  = (const float*)d_in[10];
    const float* w_ih_l0r = (const float*)d_in[11];
    const float* w_hh_l0r = (const float*)d_in[12];
    const float* b_ih_l0r = (const float*)d_in[13];
    const float* b_hh_l0r = (const float*)d_in[14];
    const float* w_ih_l1  = (const float*)d_in[15];
    const float* w_hh_l1  = (const float*)d_in[16];
    const float* b_ih_l1  = (const float*)d_in[17];
    const float* b_hh_l1  = (const float*)d_in[18];
    const float* w_ih_l1r = (const float*)d_in[19];
    const float* w_hh_l1r = (const float*)d_in[20];
    const float* b_ih_l1r = (const float*)d_in[21];
    const float* b_hh_l1r = (const float*)d_in[22];
    const float* mlp_w1   = (const float*)d_in[23];
    const float* mlp_b1   = (const float*)d_in[24];
    const float* mlp_w2   = (const float*)d_in[25];
    const float* mlp_b2   = (const float*)d_in[26];
    float* out = (float*)d_out;

    float* ws     = (float*)d_ws;
    float* x      = ws;                 // 320*400   = 128000
    float* out0   = ws + 128000;        // 320*800   = 256000
    float* out1   = ws + 384000;        // 320*800   = 256000
    float* gates  = ws + 640000;        // 320*3200  = 1024000 (reused: g0, g1, ab)
    float* biasL0 = ws + 1664000;       // 3200
    float* biasL1 = ws + 1667200;       // 3200
    float* biasAB = ws + 1670400;       // 3200

    // sentinel-fill the recurrent h-history buffers (data doubles as ready flag)
    hipMemsetAsync(out0, 0xFF, (size_t)2 * 256000 * 4, stream);

    embed_kernel<<<500, 256, 0, stream>>>(words, tags, wemb, temb, x);
    bias_kernel<<<13, 256, 0, stream>>>(b_ih_l0, b_hh_l0, b_ih_l0r, b_hh_l0r,
                                        b_ih_l1, b_hh_l1, b_ih_l1r, b_hh_l1r,
                                        mlp_b1, biasL0, biasL1, biasAB);

    dim3 gdim(50, 5);
    gemm_bias<<<gdim, 256, 0, stream>>>(x, 400, 400, w_ih_l0, w_ih_l0r, 400,
                                        biasL0, gates);
    lstm_layer<<<2 * GDW, 1024, 0, stream>>>(gates, w_hh_l0, w_hh_l0r,
                                             h0, h0 + 400, c0, c0 + 400, out0);
    gemm_bias<<<gdim, 256, 0, stream>>>(out0, 800, 800, w_ih_l1, w_ih_l1r, 800,
                                        biasL1, gates);
    lstm_layer<<<2 * GDW, 1024, 0, stream>>>(gates, w_hh_l1, w_hh_l1r,
                                             h0 + 800, h0 + 1200, c0 + 800, c0 + 1200,
                                             out1);
    gemm_bias<<<gdim, 256, 0, stream>>>(out1, 800, 800, mlp_w1, mlp_w1 + 800, 1600,
                                        biasAB, gates);

    dim3 sgrid(20, 20), sblock(16, 16);
    scores_kernel<<<sgrid, sblock, 0, stream>>>(gates, mlp_w2, mlp_b2, out);
    border_kernel<<<2, 256, 0, stream>>>(out);
}

// Round 5
// 1755.399 us; speedup vs baseline: 2.1475x; 2.1475x over previous
//
#include <hip/hip_runtime.h>
#include <hip/hip_bf16.h>
#include <hip/hip_fp16.h>

#define SEQ   320
#define HDIM  400
#define GATES 1600
#define NCOL  3200
#define GDW   16    // workgroups per direction in the recurrent kernel
#define RPW   25    // h-rows owned per workgroup (400/16)

typedef _Float16 half2v __attribute__((ext_vector_type(2)));
union H2U { unsigned u; half2v h; __half2 hh; };

// ---------------------------------------------------------------- embeddings
__global__ __launch_bounds__(256) void embed_kernel(
    const int* __restrict__ words, const int* __restrict__ tags,
    const float* __restrict__ wemb, const float* __restrict__ temb,
    float* __restrict__ x)
{
    int i = blockIdx.x * 256 + threadIdx.x;
    if (i >= SEQ * 400) return;
    int t = i / 400, c = i % 400;
    x[i] = (c < 300) ? wemb[(size_t)words[t] * 300 + c]
                     : temb[(size_t)tags[t] * 100 + (c - 300)];
}

// ---------------------------------------------------------------- bias prep
__global__ __launch_bounds__(256) void bias_kernel(
    const float* __restrict__ bihl0,  const float* __restrict__ bhhl0,
    const float* __restrict__ bihl0r, const float* __restrict__ bhhl0r,
    const float* __restrict__ bihl1,  const float* __restrict__ bhhl1,
    const float* __restrict__ bihl1r, const float* __restrict__ bhhl1r,
    const float* __restrict__ mlpb1,
    float* __restrict__ bL0, float* __restrict__ bL1, float* __restrict__ bAB)
{
    int g = blockIdx.x * 256 + threadIdx.x;
    if (g >= NCOL) return;
    if (g < GATES) {
        bL0[g] = bihl0[g] + bhhl0[g];
        bL1[g] = bihl1[g] + bhhl1[g];
        bAB[g] = mlpb1[g];
    } else {
        int q = g - GATES;
        bL0[g] = bihl0r[q] + bhhl0r[q];
        bL1[g] = bihl1r[q] + bhhl1r[q];
        bAB[g] = 0.f;
    }
}

// ---------------------------------------------------------------- tiled SGEMM
__global__ __launch_bounds__(256) void gemm_bias(
    const float* __restrict__ A, int lda, int K,
    const float* __restrict__ B0, const float* __restrict__ B1, int ldb,
    const float* __restrict__ bias, float* __restrict__ C)
{
    __shared__ float As[16][68];   // +4 pad: k-major, conflict-free
    __shared__ float Bs[16][68];
    const int m0 = blockIdx.y * 64, n0 = blockIdx.x * 64;
    const int tid = threadIdx.x, tx = tid & 15, ty = tid >> 4;
    float acc[4][4] = {};
    for (int k0 = 0; k0 < K; k0 += 16) {
        for (int i = tid; i < 1024; i += 256) {
            int r = i >> 4, c = i & 15;
            As[c][r] = A[(size_t)(m0 + r) * lda + k0 + c];
            int n = n0 + r;
            const float* brow = (n < GATES) ? (B0 + (size_t)n * ldb)
                                            : (B1 + (size_t)(n - GATES) * ldb);
            Bs[c][r] = brow[k0 + c];
        }
        __syncthreads();
#pragma unroll
        for (int kk = 0; kk < 16; ++kk) {
            float4 a4 = *(const float4*)&As[kk][ty * 4];
            float4 b4 = *(const float4*)&Bs[kk][tx * 4];
            float av[4] = {a4.x, a4.y, a4.z, a4.w};
            float bv[4] = {b4.x, b4.y, b4.z, b4.w};
#pragma unroll
            for (int i2 = 0; i2 < 4; ++i2)
#pragma unroll
                for (int j2 = 0; j2 < 4; ++j2)
                    acc[i2][j2] += av[i2] * bv[j2];
        }
        __syncthreads();
    }
#pragma unroll
    for (int i2 = 0; i2 < 4; ++i2) {
        int m = m0 + ty * 4 + i2;
#pragma unroll
        for (int j2 = 0; j2 < 4; ++j2) {
            int n = n0 + tx * 4 + j2;
            C[(size_t)m * NCOL + n] = acc[i2][j2] + bias[n];
        }
    }
}

// ---------------------------------------------------------------- recurrence
// R5: 16 WGs/dir, 25 rows/WG. Weights fp16 PACKED in 26 uint VGPRs/thread
// (fits even a 64-VGPR allocation -> spill-proof). Dot via v_dot2_f32_f16.
// h kept in LDS as packed fp16 (pollers convert). 2 barriers/step.
// h history in `out` pre-filled with 0xFFFFFFFF sentinel (data = ready flag).
__global__ __launch_bounds__(1024, 4) void lstm_layer(
    const float* __restrict__ gates,   // SEQ x 3200 (x@W_ih^T + biases)
    const float* __restrict__ whh_f, const float* __restrict__ whh_b,
    const float* __restrict__ h0f, const float* __restrict__ h0b,
    const float* __restrict__ c0f, const float* __restrict__ c0b,
    float* out)
{
    __shared__ unsigned h_pk[200];     // 400 halfs, packed 2/uint
    __shared__ float part[16][28];     // [wave][row], padded
    const int tid = threadIdx.x;
    const int dir = blockIdx.x >> 4;
    const int wg  = blockIdx.x & 15;
    const int j0  = wg * RPW;
    const float* whh = dir ? whh_b : whh_f;
    const float* h0d = dir ? h0b : h0f;
    const float* c0d = dir ? c0b : c0f;

    const int w    = tid >> 6;         // wave 0..15
    const int lane = tid & 63;
    const int g    = w & 3;            // gate
    const int kq   = w >> 2;           // k-quarter (100 elems)
    const int half = lane & 1;         // k-split within quarter: 0->[0,48) 1->[48,100)
    const int r    = lane >> 1;        // row within WG (active if r<25)
    const int jrow = j0 + (r < RPW ? r : RPW - 1);

    // ---- one-time: up to 52 W_hh weights/thread, fp16-packed into 26 uints
    unsigned wr[26];
    {
        const float2* wp = (const float2*)(whh + (size_t)(g * 400 + jrow) * 400 +
                                           kq * 100 + 48 * half);
#pragma unroll
        for (int i = 0; i < 26; ++i) {
            H2U cv; float2 f = wp[i];
            cv.hh = __floats2half2_rn(f.x, f.y);
            wr[i] = (half == 0 && i >= 24) ? 0u : cv.u;   // half=0 covers 48 elems
        }
    }

    const int pc = tid % 100;          // poll chunk (16B = 4 floats)
    const int pr = tid / 100;          // poll replica; replicas 0..3 active
    float c_prev = (tid < RPW) ? c0d[j0 + tid] : 0.f;

    for (int s = 0; s < 320; ++s) {
        const int row = dir ? (319 - s) : s;

        // gate prefetch for activation threads (independent of h_prev)
        float gv0 = 0.f, gv1 = 0.f, gv2 = 0.f, gv3 = 0.f;
        if (tid < RPW) {
            const float* gx = gates + (size_t)row * NCOL + dir * GATES + j0 + tid;
            gv0 = gx[0]; gv1 = gx[400]; gv2 = gx[800]; gv3 = gx[1200];
        }

        if (s == 0) {
            if (tid < 100) {
                float4 f = ((const float4*)h0d)[tid];
                H2U a, b;
                a.hh = __floats2half2_rn(f.x, f.y);
                b.hh = __floats2half2_rn(f.z, f.w);
                ((uint2*)h_pk)[tid] = make_uint2(a.u, b.u);
            }
        } else if (pr < 4) {
            const int rp = dir ? (row + 1) : (row - 1);
            const unsigned long long* src =
                (const unsigned long long*)(out + (size_t)rp * 800 + dir * 400) + pc * 2;
            unsigned long long a, b;
            for (;;) {
                a = __hip_atomic_load(src,     __ATOMIC_RELAXED, __HIP_MEMORY_SCOPE_AGENT);
                b = __hip_atomic_load(src + 1, __ATOMIC_RELAXED, __HIP_MEMORY_SCOPE_AGENT);
                if ((unsigned)a != 0xFFFFFFFFu && (unsigned)(a >> 32) != 0xFFFFFFFFu &&
                    (unsigned)b != 0xFFFFFFFFu && (unsigned)(b >> 32) != 0xFFFFFFFFu)
                    break;
            }
            H2U p0, p1;
            p0.hh = __floats2half2_rn(__uint_as_float((unsigned)a),
                                      __uint_as_float((unsigned)(a >> 32)));
            p1.hh = __floats2half2_rn(__uint_as_float((unsigned)b),
                                      __uint_as_float((unsigned)(b >> 32)));
            ((uint2*)h_pk)[pc] = make_uint2(p0.u, p1.u);  // replicas write same bytes
        }
        __syncthreads();

        // partial dot: 52 halves via 13 ds_read_b64 + 26 v_dot2_f32_f16
        {
            const uint2* hp2 = (const uint2*)h_pk + kq * 25 + 12 * half;
            float acc = 0.f;
#pragma unroll
            for (int i = 0; i < 13; ++i) {
                uint2 hv = hp2[i];
                H2U w0, w1, x0, x1;
                w0.u = wr[2 * i]; w1.u = wr[2 * i + 1];
                x0.u = hv.x;      x1.u = hv.y;
                acc = __builtin_amdgcn_fdot2(w0.h, x0.h, acc, false);
                acc = __builtin_amdgcn_fdot2(w1.h, x1.h, acc, false);
            }
            acc += __shfl_xor(acc, 1, 64);   // combine the two k-halves of row r
            if (half == 0 && r < RPW) part[w][r] = acc;
        }
        __syncthreads();

        if (tid < RPW) {
            float gi = gv0 + ((part[0][tid] + part[4][tid]) + (part[8][tid]  + part[12][tid]));
            float gf = gv1 + ((part[1][tid] + part[5][tid]) + (part[9][tid]  + part[13][tid]));
            float gg = gv2 + ((part[2][tid] + part[6][tid]) + (part[10][tid] + part[14][tid]));
            float go = gv3 + ((part[3][tid] + part[7][tid]) + (part[11][tid] + part[15][tid]));
            float iv = 1.f / (1.f + __expf(-gi));
            float fv = 1.f / (1.f + __expf(-gf));
            float ov = 1.f / (1.f + __expf(-go));
            float tg = 1.f - 2.f / (1.f + __expf(2.f * gg));
            c_prev = fv * c_prev + iv * tg;
            float tc = 1.f - 2.f / (1.f + __expf(2.f * c_prev));
            float hv = ov * tc;
            __hip_atomic_store((unsigned*)(out + (size_t)row * 800 + dir * 400 + j0 + tid),
                               __float_as_uint(hv), __ATOMIC_RELAXED,
                               __HIP_MEMORY_SCOPE_AGENT);
        }
        // hazards: h_pk written between barrier-2(s) and barrier-1(s+1), read
        // between barrier-1 and barrier-2; part written before barrier-2, read
        // after (act threads re-enter barrier-1 only after consuming). safe.
    }
}

// ---------------------------------------------------------------- fused scorer
__global__ __launch_bounds__(256) void scores_kernel(
    const float* __restrict__ ab, const float* __restrict__ w2,
    const float* __restrict__ b2, float* __restrict__ out)
{
    __shared__ float a_s[16 * 132];
    __shared__ float b_s[16 * 132];
    __shared__ float w_s[128];
    const int tx = threadIdx.x, ty = threadIdx.y;
    const int tid = ty * 16 + tx;
    const int n0 = blockIdx.y * 16, d0 = blockIdx.x * 16;
    float acc = 0.f;
    for (int kc = 0; kc < 1600; kc += 128) {
        for (int i = tid; i < 16 * 128; i += 256) {
            int r = i >> 7, c = i & 127;
            a_s[r * 132 + c] = ab[(size_t)(n0 + r) * NCOL + kc + c];
            b_s[r * 132 + c] = ab[(size_t)(d0 + r) * NCOL + 1600 + kc + c];
        }
        if (tid < 128) w_s[tid] = w2[kc + tid];
        __syncthreads();
#pragma unroll
        for (int k = 0; k < 128; k += 4) {
            float4 av = *(const float4*)&a_s[ty * 132 + k];
            float4 bv = *(const float4*)&b_s[tx * 132 + k];
            float4 wv = *(const float4*)&w_s[k];
            acc += fmaxf(av.x + bv.x, 0.f) * wv.x;
            acc += fmaxf(av.y + bv.y, 0.f) * wv.y;
            acc += fmaxf(av.z + bv.z, 0.f) * wv.z;
            acc += fmaxf(av.w + bv.w, 0.f) * wv.w;
        }
        __syncthreads();
    }
    int n = n0 + ty, d = d0 + tx;
    out[(size_t)(n + 1) * 321 + (d + 1)] = (n == d) ? 0.f : (acc + b2[0]);
}

__global__ void border_kernel(float* out) {
    int i = blockIdx.x * 256 + threadIdx.x;
    if (i < 321) {
        out[i]               = (i == 0) ? 1.f : 0.f;  // row 0
        out[(size_t)i * 321] = (i == 0) ? 1.f : 0.f;  // col 0
    }
}

// ---------------------------------------------------------------- launcher
extern "C" void kernel_launch(void* const* d_in, const int* in_sizes, int n_in,
                              void* d_out, int out_size, void* d_ws, size_t ws_size,
                              hipStream_t stream)
{
    const int*   words    = (const int*)d_in[0];
    const int*   tags     = (const int*)d_in[1];
    const float* wemb     = (const float*)d_in[3];
    const float* temb     = (const float*)d_in[4];
    const float* h0       = (const float*)d_in[5];
    const float* c0       = (const float*)d_in[6];
    const float* w_ih_l0  = (const float*)d_in[7];
    const float* w_hh_l0  = (const float*)d_in[8];
    const float* b_ih_l0  = (const float*)d_in[9];
    const float* b_hh_l0  = (const float*)d_in[10];
    const float* w_ih_l0r = (const float*)d_in[11];
    const float* w_hh_l0r = (const float*)d_in[12];
    const float* b_ih_l0r = (const float*)d_in[13];
    const float* b_hh_l0r = (const float*)d_in[14];
    const float* w_ih_l1  = (const float*)d_in[15];
    const float* w_hh_l1  = (const float*)d_in[16];
    const float* b_ih_l1  = (const float*)d_in[17];
    const float* b_hh_l1  = (const float*)d_in[18];
    const float* w_ih_l1r = (const float*)d_in[19];
    const float* w_hh_l1r = (const float*)d_in[20];
    const float* b_ih_l1r = (const float*)d_in[21];
    const float* b_hh_l1r = (const float*)d_in[22];
    const float* mlp_w1   = (const float*)d_in[23];
    const float* mlp_b1   = (const float*)d_in[24];
    const float* mlp_w2   = (const float*)d_in[25];
    const float* mlp_b2   = (const float*)d_in[26];
    float* out = (float*)d_out;

    float* ws     = (float*)d_ws;
    float* x      = ws;                 // 320*400   = 128000
    float* out0   = ws + 128000;        // 320*800   = 256000
    float* out1   = ws + 384000;        // 320*800   = 256000
    float* gates  = ws + 640000;        // 320*3200  = 1024000 (reused: g0, g1, ab)
    float* biasL0 = ws + 1664000;       // 3200
    float* biasL1 = ws + 1667200;       // 3200
    float* biasAB = ws + 1670400;       // 3200

    // sentinel-fill the recurrent h-history buffers (data doubles as ready flag)
    hipMemsetAsync(out0, 0xFF, (size_t)2 * 256000 * 4, stream);

    embed_kernel<<<500, 256, 0, stream>>>(words, tags, wemb, temb, x);
    bias_kernel<<<13, 256, 0, stream>>>(b_ih_l0, b_hh_l0, b_ih_l0r, b_hh_l0r,
                                        b_ih_l1, b_hh_l1, b_ih_l1r, b_hh_l1r,
                                        mlp_b1, biasL0, biasL1, biasAB);

    dim3 gdim(50, 5);
    gemm_bias<<<gdim, 256, 0, stream>>>(x, 400, 400, w_ih_l0, w_ih_l0r, 400,
                                        biasL0, gates);
    lstm_layer<<<2 * GDW, 1024, 0, stream>>>(gates, w_hh_l0, w_hh_l0r,
                                             h0, h0 + 400, c0, c0 + 400, out0);
    gemm_bias<<<gdim, 256, 0, stream>>>(out0, 800, 800, w_ih_l1, w_ih_l1r, 800,
                                        biasL1, gates);
    lstm_layer<<<2 * GDW, 1024, 0, stream>>>(gates, w_hh_l1, w_hh_l1r,
                                             h0 + 800, h0 + 1200, c0 + 800, c0 + 1200,
                                             out1);
    gemm_bias<<<gdim, 256, 0, stream>>>(out1, 800, 800, mlp_w1, mlp_w1 + 800, 1600,
                                        biasAB, gates);

    dim3 sgrid(20, 20), sblock(16, 16);
    scores_kernel<<<sgrid, sblock, 0, stream>>>(gates, mlp_w2, mlp_b2, out);
    border_kernel<<<2, 256, 0, stream>>>(out);
}

// Round 6
// 1582.305 us; speedup vs baseline: 2.3824x; 1.1094x over previous
//
#include <hip/hip_runtime.h>
#include <hip/hip_bf16.h>
#include <hip/hip_fp16.h>

#define SEQ   320
#define HDIM  400
#define GATES 1600
#define NCOL  3200
#define GDW   16    // workgroups per direction in the recurrent kernel
#define RPW   25    // h-rows owned per workgroup (400/16)

typedef _Float16 half2v __attribute__((ext_vector_type(2)));
typedef _Float16 f16x8  __attribute__((ext_vector_type(8)));
typedef float    f32x4  __attribute__((ext_vector_type(4)));
union H2U { unsigned u; half2v h; __half2 hh; };

// ---------------------------------------------------------------- embeddings -> f16 (padded K=416)
__global__ __launch_bounds__(256) void embed_f16_kernel(
    const int* __restrict__ words, const int* __restrict__ tags,
    const float* __restrict__ wemb, const float* __restrict__ temb,
    _Float16* __restrict__ xh)
{
    int i = blockIdx.x * 256 + threadIdx.x;
    if (i >= SEQ * 416) return;
    int t = i / 416, c = i % 416;
    float v = 0.f;
    if (c < 300)      v = wemb[(size_t)words[t] * 300 + c];
    else if (c < 400) v = temb[(size_t)tags[t] * 100 + (c - 300)];
    xh[i] = (_Float16)v;
}

// ---------------------------------------------------------------- weight convert fp32 -> f16 (B^T layout, zero-padded K)
__global__ __launch_bounds__(256) void cvtB_kernel(
    const float* __restrict__ B0, const float* __restrict__ B1, int ldb,
    int K, int Kp, _Float16* __restrict__ dst)
{
    int i = blockIdx.x * 256 + threadIdx.x;
    if (i >= NCOL * Kp) return;
    int n = i / Kp, k = i % Kp;
    float v = 0.f;
    if (k < K)
        v = (n < GATES) ? B0[(size_t)n * ldb + k] : B1[(size_t)(n - GATES) * ldb + k];
    dst[i] = (_Float16)v;
}

// ---------------------------------------------------------------- activation convert fp32 -> f16
__global__ __launch_bounds__(256) void cvtA_kernel(
    const float* __restrict__ src, _Float16* __restrict__ dst, int n)
{
    int i = blockIdx.x * 256 + threadIdx.x;
    if (i < n) dst[i] = (_Float16)src[i];
}

// ---------------------------------------------------------------- bias prep
__global__ __launch_bounds__(256) void bias_kernel(
    const float* __restrict__ bihl0,  const float* __restrict__ bhhl0,
    const float* __restrict__ bihl0r, const float* __restrict__ bhhl0r,
    const float* __restrict__ bihl1,  const float* __restrict__ bhhl1,
    const float* __restrict__ bihl1r, const float* __restrict__ bhhl1r,
    const float* __restrict__ mlpb1,
    float* __restrict__ bL0, float* __restrict__ bL1, float* __restrict__ bAB)
{
    int g = blockIdx.x * 256 + threadIdx.x;
    if (g >= NCOL) return;
    if (g < GATES) {
        bL0[g] = bihl0[g] + bhhl0[g];
        bL1[g] = bihl1[g] + bhhl1[g];
        bAB[g] = mlpb1[g];
    } else {
        int q = g - GATES;
        bL0[g] = bihl0r[q] + bhhl0r[q];
        bL1[g] = bihl1r[q] + bhhl1r[q];
        bAB[g] = 0.f;
    }
}

// ---------------------------------------------------------------- MFMA f16 GEMM
// C[320 x 3200] = A[320 x Kp](f16) @ B[3200 x Kp](f16, B^T layout) + bias.
// 32x64 tile/block, 4 waves: wave = (m-half, n-half). Fragment layout per
// m89/m91: A: m=lane&15,k=quad*8+j; B: n=lane&15,k=quad*8+j; D: col=lane&15,
// row=quad*4+r. fp32 accumulate.
__global__ __launch_bounds__(256) void gemm_f16(
    const _Float16* __restrict__ A, int Kp,
    const _Float16* __restrict__ B,
    const float* __restrict__ bias, float* __restrict__ C)
{
    const int tid  = threadIdx.x;
    const int w    = tid >> 6, lane = tid & 63;
    const int quad = lane >> 4, l16 = lane & 15;
    const int mb   = blockIdx.y * 32 + (w & 1) * 16;
    const int n0   = blockIdx.x * 64 + (w >> 1) * 32;
    const _Float16* Arow = A + (size_t)(mb + l16) * Kp + quad * 8;
    const _Float16* B0r  = B + (size_t)(n0 + l16) * Kp + quad * 8;
    const _Float16* B1r  = B0r + (size_t)16 * Kp;
    f32x4 acc0 = {0.f, 0.f, 0.f, 0.f}, acc1 = {0.f, 0.f, 0.f, 0.f};
#pragma unroll 4
    for (int k0 = 0; k0 < Kp; k0 += 32) {
        f16x8 a  = *(const f16x8*)(Arow + k0);
        f16x8 b0 = *(const f16x8*)(B0r + k0);
        f16x8 b1 = *(const f16x8*)(B1r + k0);
        acc0 = __builtin_amdgcn_mfma_f32_16x16x32_f16(a, b0, acc0, 0, 0, 0);
        acc1 = __builtin_amdgcn_mfma_f32_16x16x32_f16(a, b1, acc1, 0, 0, 0);
    }
    const int mr = mb + quad * 4;
    float bn0 = bias[n0 + l16], bn1 = bias[n0 + 16 + l16];
#pragma unroll
    for (int r = 0; r < 4; ++r) {
        C[(size_t)(mr + r) * NCOL + n0 + l16]      = acc0[r] + bn0;
        C[(size_t)(mr + r) * NCOL + n0 + 16 + l16] = acc1[r] + bn1;
    }
}

// ---------------------------------------------------------------- recurrence (unchanged from R5)
__global__ __launch_bounds__(1024, 4) void lstm_layer(
    const float* __restrict__ gates,   // SEQ x 3200 (x@W_ih^T + biases)
    const float* __restrict__ whh_f, const float* __restrict__ whh_b,
    const float* __restrict__ h0f, const float* __restrict__ h0b,
    const float* __restrict__ c0f, const float* __restrict__ c0b,
    float* out)
{
    __shared__ unsigned h_pk[200];     // 400 halfs, packed 2/uint
    __shared__ float part[16][28];     // [wave][row], padded
    const int tid = threadIdx.x;
    const int dir = blockIdx.x >> 4;
    const int wg  = blockIdx.x & 15;
    const int j0  = wg * RPW;
    const float* whh = dir ? whh_b : whh_f;
    const float* h0d = dir ? h0b : h0f;
    const float* c0d = dir ? c0b : c0f;

    const int w    = tid >> 6;         // wave 0..15
    const int lane = tid & 63;
    const int g    = w & 3;            // gate
    const int kq   = w >> 2;           // k-quarter (100 elems)
    const int half = lane & 1;         // k-split within quarter
    const int r    = lane >> 1;        // row within WG (active if r<25)
    const int jrow = j0 + (r < RPW ? r : RPW - 1);

    unsigned wr[26];
    {
        const float2* wp = (const float2*)(whh + (size_t)(g * 400 + jrow) * 400 +
                                           kq * 100 + 48 * half);
#pragma unroll
        for (int i = 0; i < 26; ++i) {
            H2U cv; float2 f = wp[i];
            cv.hh = __floats2half2_rn(f.x, f.y);
            wr[i] = (half == 0 && i >= 24) ? 0u : cv.u;
        }
    }

    const int pc = tid % 100;
    const int pr = tid / 100;
    float c_prev = (tid < RPW) ? c0d[j0 + tid] : 0.f;

    for (int s = 0; s < 320; ++s) {
        const int row = dir ? (319 - s) : s;

        float gv0 = 0.f, gv1 = 0.f, gv2 = 0.f, gv3 = 0.f;
        if (tid < RPW) {
            const float* gx = gates + (size_t)row * NCOL + dir * GATES + j0 + tid;
            gv0 = gx[0]; gv1 = gx[400]; gv2 = gx[800]; gv3 = gx[1200];
        }

        if (s == 0) {
            if (tid < 100) {
                float4 f = ((const float4*)h0d)[tid];
                H2U a, b;
                a.hh = __floats2half2_rn(f.x, f.y);
                b.hh = __floats2half2_rn(f.z, f.w);
                ((uint2*)h_pk)[tid] = make_uint2(a.u, b.u);
            }
        } else if (pr < 4) {
            const int rp = dir ? (row + 1) : (row - 1);
            const unsigned long long* src =
                (const unsigned long long*)(out + (size_t)rp * 800 + dir * 400) + pc * 2;
            unsigned long long a, b;
            for (;;) {
                a = __hip_atomic_load(src,     __ATOMIC_RELAXED, __HIP_MEMORY_SCOPE_AGENT);
                b = __hip_atomic_load(src + 1, __ATOMIC_RELAXED, __HIP_MEMORY_SCOPE_AGENT);
                if ((unsigned)a != 0xFFFFFFFFu && (unsigned)(a >> 32) != 0xFFFFFFFFu &&
                    (unsigned)b != 0xFFFFFFFFu && (unsigned)(b >> 32) != 0xFFFFFFFFu)
                    break;
            }
            H2U p0, p1;
            p0.hh = __floats2half2_rn(__uint_as_float((unsigned)a),
                                      __uint_as_float((unsigned)(a >> 32)));
            p1.hh = __floats2half2_rn(__uint_as_float((unsigned)b),
                                      __uint_as_float((unsigned)(b >> 32)));
            ((uint2*)h_pk)[pc] = make_uint2(p0.u, p1.u);
        }
        __syncthreads();

        {
            const uint2* hp2 = (const uint2*)h_pk + kq * 25 + 12 * half;
            float acc = 0.f;
#pragma unroll
            for (int i = 0; i < 13; ++i) {
                uint2 hv = hp2[i];
                H2U w0, w1, x0, x1;
                w0.u = wr[2 * i]; w1.u = wr[2 * i + 1];
                x0.u = hv.x;      x1.u = hv.y;
                acc = __builtin_amdgcn_fdot2(w0.h, x0.h, acc, false);
                acc = __builtin_amdgcn_fdot2(w1.h, x1.h, acc, false);
            }
            acc += __shfl_xor(acc, 1, 64);
            if (half == 0 && r < RPW) part[w][r] = acc;
        }
        __syncthreads();

        if (tid < RPW) {
            float gi = gv0 + ((part[0][tid] + part[4][tid]) + (part[8][tid]  + part[12][tid]));
            float gf = gv1 + ((part[1][tid] + part[5][tid]) + (part[9][tid]  + part[13][tid]));
            float gg = gv2 + ((part[2][tid] + part[6][tid]) + (part[10][tid] + part[14][tid]));
            float go = gv3 + ((part[3][tid] + part[7][tid]) + (part[11][tid] + part[15][tid]));
            float iv = 1.f / (1.f + __expf(-gi));
            float fv = 1.f / (1.f + __expf(-gf));
            float ov = 1.f / (1.f + __expf(-go));
            float tg = 1.f - 2.f / (1.f + __expf(2.f * gg));
            c_prev = fv * c_prev + iv * tg;
            float tc = 1.f - 2.f / (1.f + __expf(2.f * c_prev));
            float hv = ov * tc;
            __hip_atomic_store((unsigned*)(out + (size_t)row * 800 + dir * 400 + j0 + tid),
                               __float_as_uint(hv), __ATOMIC_RELAXED,
                               __HIP_MEMORY_SCOPE_AGENT);
        }
    }
}

// ---------------------------------------------------------------- fused scorer
__global__ __launch_bounds__(256) void scores_kernel(
    const float* __restrict__ ab, const float* __restrict__ w2,
    const float* __restrict__ b2, float* __restrict__ out)
{
    __shared__ float a_s[16 * 132];
    __shared__ float b_s[16 * 132];
    __shared__ float w_s[128];
    const int tx = threadIdx.x, ty = threadIdx.y;
    const int tid = ty * 16 + tx;
    const int n0 = blockIdx.y * 16, d0 = blockIdx.x * 16;
    float acc = 0.f;
    for (int kc = 0; kc < 1600; kc += 128) {
        for (int i = tid; i < 16 * 128; i += 256) {
            int r = i >> 7, c = i & 127;
            a_s[r * 132 + c] = ab[(size_t)(n0 + r) * NCOL + kc + c];
            b_s[r * 132 + c] = ab[(size_t)(d0 + r) * NCOL + 1600 + kc + c];
        }
        if (tid < 128) w_s[tid] = w2[kc + tid];
        __syncthreads();
#pragma unroll
        for (int k = 0; k < 128; k += 4) {
            float4 av = *(const float4*)&a_s[ty * 132 + k];
            float4 bv = *(const float4*)&b_s[tx * 132 + k];
            float4 wv = *(const float4*)&w_s[k];
            acc += fmaxf(av.x + bv.x, 0.f) * wv.x;
            acc += fmaxf(av.y + bv.y, 0.f) * wv.y;
            acc += fmaxf(av.z + bv.z, 0.f) * wv.z;
            acc += fmaxf(av.w + bv.w, 0.f) * wv.w;
        }
        __syncthreads();
    }
    int n = n0 + ty, d = d0 + tx;
    out[(size_t)(n + 1) * 321 + (d + 1)] = (n == d) ? 0.f : (acc + b2[0]);
}

__global__ void border_kernel(float* out) {
    int i = blockIdx.x * 256 + threadIdx.x;
    if (i < 321) {
        out[i]               = (i == 0) ? 1.f : 0.f;  // row 0
        out[(size_t)i * 321] = (i == 0) ? 1.f : 0.f;  // col 0
    }
}

// ---------------------------------------------------------------- launcher
extern "C" void kernel_launch(void* const* d_in, const int* in_sizes, int n_in,
                              void* d_out, int out_size, void* d_ws, size_t ws_size,
                              hipStream_t stream)
{
    const int*   words    = (const int*)d_in[0];
    const int*   tags     = (const int*)d_in[1];
    const float* wemb     = (const float*)d_in[3];
    const float* temb     = (const float*)d_in[4];
    const float* h0       = (const float*)d_in[5];
    const float* c0       = (const float*)d_in[6];
    const float* w_ih_l0  = (const float*)d_in[7];
    const float* w_hh_l0  = (const float*)d_in[8];
    const float* b_ih_l0  = (const float*)d_in[9];
    const float* b_hh_l0  = (const float*)d_in[10];
    const float* w_ih_l0r = (const float*)d_in[11];
    const float* w_hh_l0r = (const float*)d_in[12];
    const float* b_ih_l0r = (const float*)d_in[13];
    const float* b_hh_l0r = (const float*)d_in[14];
    const float* w_ih_l1  = (const float*)d_in[15];
    const float* w_hh_l1  = (const float*)d_in[16];
    const float* b_ih_l1  = (const float*)d_in[17];
    const float* b_hh_l1  = (const float*)d_in[18];
    const float* w_ih_l1r = (const float*)d_in[19];
    const float* w_hh_l1r = (const float*)d_in[20];
    const float* b_ih_l1r = (const float*)d_in[21];
    const float* b_hh_l1r = (const float*)d_in[22];
    const float* mlp_w1   = (const float*)d_in[23];
    const float* mlp_b1   = (const float*)d_in[24];
    const float* mlp_w2   = (const float*)d_in[25];
    const float* mlp_b2   = (const float*)d_in[26];
    float* out = (float*)d_out;

    float* ws     = (float*)d_ws;
    float* out0   = ws + 128000;        // 320*800
    float* out1   = ws + 384000;        // 320*800
    float* gates  = ws + 640000;        // 320*3200 (reused: g0, g1, ab)
    float* biasL0 = ws + 1664000;
    float* biasL1 = ws + 1667200;
    float* biasAB = ws + 1670400;
    _Float16* Ah  = (_Float16*)(ws + 1673600);  // up to 320*800 halves
    _Float16* Bh  = (_Float16*)(ws + 1801600);  // up to 3200*800 halves

    // sentinel-fill the recurrent h-history buffers (data doubles as ready flag)
    hipMemsetAsync(out0, 0xFF, (size_t)2 * 256000 * 4, stream);

    embed_f16_kernel<<<520, 256, 0, stream>>>(words, tags, wemb, temb, Ah);
    bias_kernel<<<13, 256, 0, stream>>>(b_ih_l0, b_hh_l0, b_ih_l0r, b_hh_l0r,
                                        b_ih_l1, b_hh_l1, b_ih_l1r, b_hh_l1r,
                                        mlp_b1, biasL0, biasL1, biasAB);

    // ---- layer-0 input gates: x @ [w_ih_l0; w_ih_l0r]^T + biases (K=400->416)
    cvtB_kernel<<<(NCOL * 416 + 255) / 256, 256, 0, stream>>>(
        w_ih_l0, w_ih_l0r, 400, 400, 416, Bh);
    gemm_f16<<<dim3(50, 10), 256, 0, stream>>>(Ah, 416, Bh, biasL0, gates);
    lstm_layer<<<2 * GDW, 1024, 0, stream>>>(gates, w_hh_l0, w_hh_l0r,
                                             h0, h0 + 400, c0, c0 + 400, out0);

    // ---- layer-1 input gates: out0 @ [w_ih_l1; w_ih_l1r]^T + biases (K=800)
    cvtA_kernel<<<1000, 256, 0, stream>>>(out0, Ah, 256000);
    cvtB_kernel<<<(NCOL * 800 + 255) / 256, 256, 0, stream>>>(
        w_ih_l1, w_ih_l1r, 800, 800, 800, Bh);
    gemm_f16<<<dim3(50, 10), 256, 0, stream>>>(Ah, 800, Bh, biasL1, gates);
    lstm_layer<<<2 * GDW, 1024, 0, stream>>>(gates, w_hh_l1, w_hh_l1r,
                                             h0 + 800, h0 + 1200, c0 + 800, c0 + 1200,
                                             out1);

    // ---- [a | b] = hv @ [w1a; w1b]^T (+ mlp_b1 folded into a-half) (K=800)
    cvtA_kernel<<<1000, 256, 0, stream>>>(out1, Ah, 256000);
    cvtB_kernel<<<(NCOL * 800 + 255) / 256, 256, 0, stream>>>(
        mlp_w1, mlp_w1 + 800, 1600, 800, 800, Bh);
    gemm_f16<<<dim3(50, 10), 256, 0, stream>>>(Ah, 800, Bh, biasAB, gates);

    dim3 sgrid(20, 20), sblock(16, 16);
    scores_kernel<<<sgrid, sblock, 0, stream>>>(gates, mlp_w2, mlp_b2, out);
    border_kernel<<<2, 256, 0, stream>>>(out);
}

// Round 7
// 1356.654 us; speedup vs baseline: 2.7787x; 1.1663x over previous
//
#include <hip/hip_runtime.h>
#include <hip/hip_bf16.h>
#include <hip/hip_fp16.h>

#define SEQ   320
#define GATES 1600
#define NCOL  3200
#define GDW   16    // workgroups per direction in the recurrent kernel
#define RPW   25    // h-rows owned per workgroup (400/16)

typedef _Float16 half2v __attribute__((ext_vector_type(2)));
typedef _Float16 f16x8  __attribute__((ext_vector_type(8)));
typedef float    f32x4  __attribute__((ext_vector_type(4)));
union H2U { unsigned u; half2v h; __half2 hh; };

// ---------------------------------------------------------------- prep: embed->f16, bias sums, cvt W_ih_l0
__global__ __launch_bounds__(256) void prep_kernel(
    const int* __restrict__ words, const int* __restrict__ tags,
    const float* __restrict__ wemb, const float* __restrict__ temb,
    _Float16* __restrict__ Ah0,
    const float* __restrict__ bihl0,  const float* __restrict__ bhhl0,
    const float* __restrict__ bihl0r, const float* __restrict__ bhhl0r,
    const float* __restrict__ bihl1,  const float* __restrict__ bhhl1,
    const float* __restrict__ bihl1r, const float* __restrict__ bhhl1r,
    const float* __restrict__ mlpb1,
    float* __restrict__ bL0, float* __restrict__ bL1, float* __restrict__ bAB,
    const float* __restrict__ wih0, const float* __restrict__ wih0r,
    _Float16* __restrict__ BhA)
{
    const int b = blockIdx.x, t = threadIdx.x;
    if (b < 520) {                       // embeddings -> Ah0 (320 x 416, zero-pad)
        int i = b * 256 + t;
        if (i >= SEQ * 416) return;
        int tt = i / 416, c = i % 416;
        float v = 0.f;
        if (c < 300)      v = wemb[(size_t)words[tt] * 300 + c];
        else if (c < 400) v = temb[(size_t)tags[tt] * 100 + (c - 300)];
        Ah0[i] = (_Float16)v;
    } else if (b < 533) {                // bias sums
        int g = (b - 520) * 256 + t;
        if (g >= NCOL) return;
        if (g < GATES) {
            bL0[g] = bihl0[g] + bhhl0[g];
            bL1[g] = bihl1[g] + bhhl1[g];
            bAB[g] = mlpb1[g];
        } else {
            int q = g - GATES;
            bL0[g] = bihl0r[q] + bhhl0r[q];
            bL1[g] = bihl1r[q] + bhhl1r[q];
            bAB[g] = 0.f;
        }
    } else {                             // W_ih_l0 -> fp16 (3200 x 416, zero-pad K)
        int i = (b - 533) * 256 + t;
        if (i >= NCOL * 416) return;
        int n = i / 416, k = i % 416;
        float v = 0.f;
        if (k < 400)
            v = (n < GATES) ? wih0[(size_t)n * 400 + k]
                            : wih0r[(size_t)(n - GATES) * 400 + k];
        BhA[i] = (_Float16)v;
    }
}

// ---------------------------------------------------------------- cvt W_ih_l1 -> BhB, mlp_w1 -> BhA
__global__ __launch_bounds__(256) void cvt2_kernel(
    const float* __restrict__ wih1, const float* __restrict__ wih1r,
    _Float16* __restrict__ BhB,
    const float* __restrict__ mlpw1, _Float16* __restrict__ BhA)
{
    const int b = blockIdx.x, t = threadIdx.x;
    if (b < 10000) {
        int i = b * 256 + t;
        if (i >= NCOL * 800) return;
        int n = i / 800, k = i % 800;
        BhB[i] = (_Float16)((n < GATES) ? wih1[(size_t)n * 800 + k]
                                        : wih1r[(size_t)(n - GATES) * 800 + k]);
    } else {
        int i = (b - 10000) * 256 + t;
        if (i >= NCOL * 800) return;
        int n = i / 800, k = i % 800;
        BhA[i] = (_Float16)((n < GATES) ? mlpw1[(size_t)n * 1600 + k]
                                        : mlpw1[(size_t)(n - GATES) * 1600 + 800 + k]);
    }
}

// ---------------------------------------------------------------- MFMA f16 GEMM (as R6, verified)
__global__ __launch_bounds__(256) void gemm_f16(
    const _Float16* __restrict__ A, int Kp,
    const _Float16* __restrict__ B,
    const float* __restrict__ bias, float* __restrict__ C)
{
    const int tid  = threadIdx.x;
    const int w    = tid >> 6, lane = tid & 63;
    const int quad = lane >> 4, l16 = lane & 15;
    const int mb   = blockIdx.y * 32 + (w & 1) * 16;
    const int n0   = blockIdx.x * 64 + (w >> 1) * 32;
    const _Float16* Arow = A + (size_t)(mb + l16) * Kp + quad * 8;
    const _Float16* B0r  = B + (size_t)(n0 + l16) * Kp + quad * 8;
    const _Float16* B1r  = B0r + (size_t)16 * Kp;
    f32x4 acc0 = {0.f, 0.f, 0.f, 0.f}, acc1 = {0.f, 0.f, 0.f, 0.f};
#pragma unroll 4
    for (int k0 = 0; k0 < Kp; k0 += 32) {
        f16x8 a  = *(const f16x8*)(Arow + k0);
        f16x8 b0 = *(const f16x8*)(B0r + k0);
        f16x8 b1 = *(const f16x8*)(B1r + k0);
        acc0 = __builtin_amdgcn_mfma_f32_16x16x32_f16(a, b0, acc0, 0, 0, 0);
        acc1 = __builtin_amdgcn_mfma_f32_16x16x32_f16(a, b1, acc1, 0, 0, 0);
    }
    const int mr = mb + quad * 4;
    float bn0 = bias[n0 + l16], bn1 = bias[n0 + 16 + l16];
#pragma unroll
    for (int r = 0; r < 4; ++r) {
        C[(size_t)(mr + r) * NCOL + n0 + l16]      = acc0[r] + bn0;
        C[(size_t)(mr + r) * NCOL + n0 + 16 + l16] = acc1[r] + bn1;
    }
}

// ---------------------------------------------------------------- recurrence
// R7: R5's partition/dot/act kept; exchange medium replaced by per-producer,
// 64B line-aligned fp16 blocks: ex[((dir*16+p)*320+row)*16 + d], d<13 used
// (25 halves packed in 13 dwords, pad half = 0). One private L3 line per
// producer per step -> no false sharing; 208 pollers (one dword each) write
// straight into LDS h_pk via 16-bit stores. Own rows short-circuit via LDS.
__global__ __launch_bounds__(1024, 4) void lstm_layer(
    const float* __restrict__ gates,   // SEQ x 3200 (x@W_ih^T + biases)
    const float* __restrict__ whh_f, const float* __restrict__ whh_b,
    const float* __restrict__ h0f, const float* __restrict__ h0b,
    const float* __restrict__ c0f, const float* __restrict__ c0b,
    unsigned* __restrict__ ex,         // this layer's exchange region
    _Float16* __restrict__ ah)         // SEQ x 800 fp16 h (input to next GEMM)
{
    __shared__ unsigned h_pk[200];     // 400 halfs of h_prev
    __shared__ float part[16][28];
    unsigned short* hs = (unsigned short*)h_pk;
    const int tid = threadIdx.x;
    const int dir = blockIdx.x >> 4;
    const int wg  = blockIdx.x & 15;
    const int j0  = wg * RPW;
    const float* whh = dir ? whh_b : whh_f;
    const float* h0d = dir ? h0b : h0f;
    const float* c0d = dir ? c0b : c0f;

    const int w    = tid >> 6;         // wave 0..15
    const int lane = tid & 63;
    const int g    = w & 3;            // gate
    const int kq   = w >> 2;           // k-quarter (100 elems)
    const int half = lane & 1;         // k-split within quarter
    const int r    = lane >> 1;        // row within WG (active if r<25)
    const int jrow = j0 + (r < RPW ? r : RPW - 1);

    // one-time: 52 W_hh weights/thread, fp16-packed into 26 uints (spill-proof)
    unsigned wr[26];
    {
        const float2* wp = (const float2*)(whh + (size_t)(g * 400 + jrow) * 400 +
                                           kq * 100 + 48 * half);
#pragma unroll
        for (int i = 0; i < 26; ++i) {
            H2U cv; float2 f = wp[i];
            cv.hh = __floats2half2_rn(f.x, f.y);
            wr[i] = (half == 0 && i >= 24) ? 0u : cv.u;
        }
    }

    const int pp = tid / 13;           // producer block polled (tid<208)
    const int pd = tid - pp * 13;      // dword within block
    float c_prev = (tid < RPW) ? c0d[j0 + tid] : 0.f;

    for (int s = 0; s < 320; ++s) {
        const int row = dir ? (319 - s) : s;

        // gate prefetch (independent of h_prev, overlaps the poll)
        float gv0 = 0.f, gv1 = 0.f, gv2 = 0.f, gv3 = 0.f;
        if (tid < RPW) {
            const float* gx = gates + (size_t)row * NCOL + dir * GATES + j0 + tid;
            gv0 = gx[0]; gv1 = gx[400]; gv2 = gx[800]; gv3 = gx[1200];
        }

        if (s == 0) {
            if (tid < 100) {
                float4 f = ((const float4*)h0d)[tid];
                H2U a, b;
                a.hh = __floats2half2_rn(f.x, f.y);
                b.hh = __floats2half2_rn(f.z, f.w);
                ((uint2*)h_pk)[tid] = make_uint2(a.u, b.u);
            }
        } else if (tid < 208 && pp != wg) {
            const int rp = dir ? (row + 1) : (row - 1);
            const unsigned* src = ex + (((size_t)dir * GDW + pp) * SEQ + rp) * 16 + pd;
            unsigned v;
            for (;;) {
                v = __hip_atomic_load(src, __ATOMIC_RELAXED, __HIP_MEMORY_SCOPE_AGENT);
                if ((v & 0xFFFFu) != 0xFFFFu &&
                    (pd == 12 || (v >> 16) != 0xFFFFu)) break;
            }
            const int hb = pp * RPW + pd * 2;
            hs[hb] = (unsigned short)(v & 0xFFFFu);
            if (pd < 12) hs[hb + 1] = (unsigned short)(v >> 16);
        }
        __syncthreads();

        // partial dot: 52 halves via 13 ds_read_b64 + 26 v_dot2_f32_f16
        {
            const uint2* hp2 = (const uint2*)h_pk + kq * 25 + 12 * half;
            float acc = 0.f;
#pragma unroll
            for (int i = 0; i < 13; ++i) {
                uint2 hv2 = hp2[i];
                H2U w0, w1, x0, x1;
                w0.u = wr[2 * i]; w1.u = wr[2 * i + 1];
                x0.u = hv2.x;     x1.u = hv2.y;
                acc = __builtin_amdgcn_fdot2(w0.h, x0.h, acc, false);
                acc = __builtin_amdgcn_fdot2(w1.h, x1.h, acc, false);
            }
            acc += __shfl_xor(acc, 1, 64);
            if (half == 0 && r < RPW) part[w][r] = acc;
        }
        __syncthreads();

        // activation + exchange store (wave 0 only)
        float hv = 0.f;
        if (tid < RPW) {
            float gi = gv0 + ((part[0][tid] + part[4][tid]) + (part[8][tid]  + part[12][tid]));
            float gf = gv1 + ((part[1][tid] + part[5][tid]) + (part[9][tid]  + part[13][tid]));
            float gg = gv2 + ((part[2][tid] + part[6][tid]) + (part[10][tid] + part[14][tid]));
            float go = gv3 + ((part[3][tid] + part[7][tid]) + (part[11][tid] + part[15][tid]));
            float iv = 1.f / (1.f + __expf(-gi));
            float fv = 1.f / (1.f + __expf(-gf));
            float ov = 1.f / (1.f + __expf(-go));
            float tg = 1.f - 2.f / (1.f + __expf(2.f * gg));
            c_prev = fv * c_prev + iv * tg;
            float tc = 1.f - 2.f / (1.f + __expf(2.f * c_prev));
            hv = ov * tc;
        }
        if (w == 0) {
            int i0 = 2 * lane     < 63 ? 2 * lane     : 63;
            int i1 = 2 * lane + 1 < 63 ? 2 * lane + 1 : 63;
            float xlo = __shfl(hv, i0, 64);
            float xhi = __shfl(hv, i1, 64);
            if (lane < 13) {                 // one private 64B line per step
                H2U pk;
                pk.hh = __floats2half2_rn(xlo, (2 * lane + 1 < RPW) ? xhi : 0.f);
                __hip_atomic_store(ex + (((size_t)dir * GDW + wg) * SEQ + row) * 16 + lane,
                                   pk.u, __ATOMIC_RELAXED, __HIP_MEMORY_SCOPE_AGENT);
            }
            if (tid < RPW) {                 // fp16 h for next GEMM + own-row LDS
                ah[(size_t)row * 800 + dir * 400 + j0 + tid] = (_Float16)hv;
                H2U o; o.hh = __floats2half2_rn(hv, 0.f);
                hs[RPW * wg + tid] = (unsigned short)(o.u & 0xFFFFu);
            }
        }
        // hazards: h_pk written (pollers + act own-range) between barrier-2(s)
        // and barrier-1(s+1), read between barrier-1 and barrier-2; part[]
        // written pre-barrier-2, read post; disjoint LDS ranges. safe.
    }
}

// ---------------------------------------------------------------- fused scorer (+ border rows)
__global__ __launch_bounds__(256) void scores_kernel(
    const float* __restrict__ ab, const float* __restrict__ w2,
    const float* __restrict__ b2, float* __restrict__ out)
{
    if (blockIdx.y == 20) {              // border: row 0 / col 0
        int i = blockIdx.x * 256 + threadIdx.y * 16 + threadIdx.x;
        if (blockIdx.x < 2 && i < 321) {
            out[i]               = (i == 0) ? 1.f : 0.f;
            out[(size_t)i * 321] = (i == 0) ? 1.f : 0.f;
        }
        return;
    }
    __shared__ float a_s[16 * 132];
    __shared__ float b_s[16 * 132];
    __shared__ float w_s[128];
    const int tx = threadIdx.x, ty = threadIdx.y;
    const int tid = ty * 16 + tx;
    const int n0 = blockIdx.y * 16, d0 = blockIdx.x * 16;
    float acc = 0.f;
    for (int kc = 0; kc < 1600; kc += 128) {
        for (int i = tid; i < 16 * 128; i += 256) {
            int r = i >> 7, c = i & 127;
            a_s[r * 132 + c] = ab[(size_t)(n0 + r) * NCOL + kc + c];
            b_s[r * 132 + c] = ab[(size_t)(d0 + r) * NCOL + 1600 + kc + c];
        }
        if (tid < 128) w_s[tid] = w2[kc + tid];
        __syncthreads();
#pragma unroll
        for (int k = 0; k < 128; k += 4) {
            float4 av = *(const float4*)&a_s[ty * 132 + k];
            float4 bv = *(const float4*)&b_s[tx * 132 + k];
            float4 wv = *(const float4*)&w_s[k];
            acc += fmaxf(av.x + bv.x, 0.f) * wv.x;
            acc += fmaxf(av.y + bv.y, 0.f) * wv.y;
            acc += fmaxf(av.z + bv.z, 0.f) * wv.z;
            acc += fmaxf(av.w + bv.w, 0.f) * wv.w;
        }
        __syncthreads();
    }
    int n = n0 + ty, d = d0 + tx;
    out[(size_t)(n + 1) * 321 + (d + 1)] = (n == d) ? 0.f : (acc + b2[0]);
}

// ---------------------------------------------------------------- launcher
extern "C" void kernel_launch(void* const* d_in, const int* in_sizes, int n_in,
                              void* d_out, int out_size, void* d_ws, size_t ws_size,
                              hipStream_t stream)
{
    const int*   words    = (const int*)d_in[0];
    const int*   tags     = (const int*)d_in[1];
    const float* wemb     = (const float*)d_in[3];
    const float* temb     = (const float*)d_in[4];
    const float* h0       = (const float*)d_in[5];
    const float* c0       = (const float*)d_in[6];
    const float* w_ih_l0  = (const float*)d_in[7];
    const float* w_hh_l0  = (const float*)d_in[8];
    const float* b_ih_l0  = (const float*)d_in[9];
    const float* b_hh_l0  = (const float*)d_in[10];
    const float* w_ih_l0r = (const float*)d_in[11];
    const float* w_hh_l0r = (const float*)d_in[12];
    const float* b_ih_l0r = (const float*)d_in[13];
    const float* b_hh_l0r = (const float*)d_in[14];
    const float* w_ih_l1  = (const float*)d_in[15];
    const float* w_hh_l1  = (const float*)d_in[16];
    const float* b_ih_l1  = (const float*)d_in[17];
    const float* b_hh_l1  = (const float*)d_in[18];
    const float* w_ih_l1r = (const float*)d_in[19];
    const float* w_hh_l1r = (const float*)d_in[20];
    const float* b_ih_l1r = (const float*)d_in[21];
    const float* b_hh_l1r = (const float*)d_in[22];
    const float* mlp_w1   = (const float*)d_in[23];
    const float* mlp_b1   = (const float*)d_in[24];
    const float* mlp_w2   = (const float*)d_in[25];
    const float* mlp_b2   = (const float*)d_in[26];
    float* out = (float*)d_out;

    float* ws      = (float*)d_ws;
    float*    gates  = ws;                              // 320*3200 = 1,024,000 f32
    float*    biasL0 = ws + 1024000;
    float*    biasL1 = ws + 1027200;
    float*    biasAB = ws + 1030400;
    unsigned* ex     = (unsigned*)(ws + 1033600);       // 2 layers x 163,840 uints
    _Float16* Ah0    = (_Float16*)(ws + 1361280);       // 320*416 halves
    _Float16* Ah1    = (_Float16*)(ws + 1427840);       // 320*800 halves
    _Float16* Ah2    = (_Float16*)(ws + 1555840);       // 320*800 halves
    _Float16* BhA    = (_Float16*)(ws + 1683840);       // up to 3200*800 halves
    _Float16* BhB    = (_Float16*)(ws + 2963840);       // 3200*800 halves
    unsigned* ex0 = ex, *ex1 = ex + 163840;

    // sentinel-fill the exchange blocks (data doubles as ready flag)
    hipMemsetAsync(ex, 0xFF, 327680u * 4, stream);

    prep_kernel<<<5733, 256, 0, stream>>>(
        words, tags, wemb, temb, Ah0,
        b_ih_l0, b_hh_l0, b_ih_l0r, b_hh_l0r,
        b_ih_l1, b_hh_l1, b_ih_l1r, b_hh_l1r,
        mlp_b1, biasL0, biasL1, biasAB, w_ih_l0, w_ih_l0r, BhA);

    gemm_f16<<<dim3(50, 10), 256, 0, stream>>>(Ah0, 416, BhA, biasL0, gates);
    cvt2_kernel<<<20000, 256, 0, stream>>>(w_ih_l1, w_ih_l1r, BhB, mlp_w1, BhA);
    lstm_layer<<<2 * GDW, 1024, 0, stream>>>(gates, w_hh_l0, w_hh_l0r,
                                             h0, h0 + 400, c0, c0 + 400, ex0, Ah1);
    gemm_f16<<<dim3(50, 10), 256, 0, stream>>>(Ah1, 800, BhB, biasL1, gates);
    lstm_layer<<<2 * GDW, 1024, 0, stream>>>(gates, w_hh_l1, w_hh_l1r,
                                             h0 + 800, h0 + 1200, c0 + 800, c0 + 1200,
                                             ex1, Ah2);
    gemm_f16<<<dim3(50, 10), 256, 0, stream>>>(Ah2, 800, BhA, biasAB, gates);

    scores_kernel<<<dim3(20, 21), dim3(16, 16), 0, stream>>>(gates, mlp_w2, mlp_b2, out);
}